// Round 9
// baseline (310.908 us; speedup 1.0000x reference)
//
#include <hip/hip_runtime.h>

#define HW 64
#define CIN 256
#define OC1 128
#define NJ 49
#define KZ 8                 // K-split: each conv1 block does 32 ic x 49 taps
#define CELLS 56             // shorts per col-cell: 32 ic + 24 pad (112B, 16B-mult)
#define CELLW 28             // words per cell
#define BUFW (80 * CELLW)    // 2240 words = 8,960 B per buffer

typedef short bf16x8 __attribute__((ext_vector_type(8)));
typedef float f32x4 __attribute__((ext_vector_type(4)));

__device__ __forceinline__ unsigned f2bf_pack(float a, float b) {
    unsigned ua = __float_as_uint(a);
    ua += 0x7FFF + ((ua >> 16) & 1);
    unsigned ub = __float_as_uint(b);
    ub += 0x7FFF + ((ub >> 16) & 1);
    return (ua >> 16) | (ub & 0xFFFF0000u);
}

__device__ __forceinline__ unsigned short f2bf(float a) {
    unsigned u = __float_as_uint(a);
    u += 0x7FFF + ((u >> 16) & 1);
    return (unsigned short)(u >> 16);
}

// ---------------------------------------------------------------------------
// w1 fp32 [128 oc][256 ic][49 tap] -> w1t bf16 [49][128 oc][256 ic]
// ---------------------------------------------------------------------------
__global__ __launch_bounds__(256) void wtrans_kernel(const float* __restrict__ w1,
                                                     unsigned short* __restrict__ w1t) {
    __shared__ float ws[128 * 49];    // [ic-half 128][tap 49]
    const int oc = blockIdx.x >> 1, ih = blockIdx.x & 1;
    const float4* src = (const float4*)(w1 + ((size_t)oc * 256 + ih * 128) * 49);
    for (int f = threadIdx.x; f < 1568; f += 256)
        *(float4*)&ws[4 * f] = src[f];
    __syncthreads();
    for (int k = threadIdx.x; k < 128 * 49; k += 256) {
        int tap = k / 128, ic = k - tap * 128;   // stride 49 mod 32 = 17: conflict-free
        w1t[((size_t)tap * 128 + oc) * 256 + ih * 128 + ic] = f2bf(ws[ic * 49 + tap]);
    }
}

// ---------------------------------------------------------------------------
// conv1 implicit GEMM, bf16 MFMA 16x16x32, KZ=8, small-tile/high-TLP variant.
// grid (64 h, 8 kz, 4 b) = 2048 blocks; block 256 = 4 waves.
// Block: 128 oc x 64 px (ONE h row). Wave: 64 oc x 32 px -> acc = 32 AGPR
// (R8's 64-AGPR tile left only 2 waves/SIMD; this targets 3-4 waves/SIMD
// + 3-4 blocks/CU so barrier phases stagger across blocks).
// Staging: ISSUE global loads at u-start into packed regs, taps overlap,
// WRITE to other LDS buffer, 1 barrier per u. wf loads inline per tap.
// P bf16 [kz][b][oc][h][w] partials.
// ---------------------------------------------------------------------------
__global__ __launch_bounds__(256) void conv1_mfma_kernel(
    const float* __restrict__ x, const unsigned short* __restrict__ w1t,
    unsigned short* __restrict__ P)
{
    __shared__ unsigned xs[2 * BUFW];   // 17,920 B

    const int h = blockIdx.x, kz = blockIdx.y, b = blockIdx.z;
    const int t = threadIdx.x;
    const int lane = t & 63, wv = t >> 6;
    const int oc_off = (wv & 1) * 64;
    const int px_off = (wv >> 1) * 32;
    const int l15 = lane & 15, quad = lane >> 4;

    f32x4 acc[4][2];
    #pragma unroll
    for (int i = 0; i < 4; ++i)
        #pragma unroll
        for (int j = 0; j < 2; ++j) acc[i][j] = (f32x4){0.f, 0.f, 0.f, 0.f};

    const float* xb = x + ((size_t)b * CIN + kz * 32) * 4096;
    const unsigned short* wbase = w1t + (size_t)(oc_off + l15) * 256 + kz * 32 + quad * 8;

    // 640 slots (8 icq x 80 col), 256 threads -> 2.5 slots/thread (3rd predicated)
    uint2 pk[3];

    auto ISSUE = [&](int u) {
        #pragma unroll
        for (int i = 0; i < 3; ++i) {
            int f = t + i * 256;
            if (f < 640) {
                int icq = f / 80, col = f - icq * 80;
                int r = h + 2 * u - 6;
                int c = col - 8;
                float v0 = 0.f, v1 = 0.f, v2 = 0.f, v3 = 0.f;
                if ((unsigned)r < 64u && (unsigned)c < 64u) {
                    const float* p = xb + (size_t)(4 * icq) * 4096 + r * 64 + c;
                    v0 = p[0]; v1 = p[4096]; v2 = p[8192]; v3 = p[12288];
                }
                pk[i] = make_uint2(f2bf_pack(v0, v1), f2bf_pack(v2, v3));
            }
        }
    };
    auto WRITE = [&](unsigned* buf) {
        #pragma unroll
        for (int i = 0; i < 3; ++i) {
            int f = t + i * 256;
            if (f < 640) {
                int icq = f / 80, col = f - icq * 80;
                *(uint2*)&buf[col * CELLW + 2 * icq] = pk[i];
            }
        }
    };

    ISSUE(0);
    WRITE(&xs[0]);
    __syncthreads();

    for (int u = 0; u < 7; ++u) {
        unsigned* cur = &xs[(u & 1) * BUFW];
        if (u < 6) ISSUE(u + 1);         // loads fly under the tap loop

        #pragma unroll
        for (int v = 0; v < 7; ++v) {
            const unsigned short* wp = wbase + (size_t)(u * 7 + v) * (128 * 256);
            bf16x8 wf[4];
            #pragma unroll
            for (int of = 0; of < 4; ++of)
                wf[of] = *(const bf16x8*)(wp + of * (16 * 256));

            bf16x8 xf[2];
            #pragma unroll
            for (int pf = 0; pf < 2; ++pf) {
                const int scol = px_off + pf * 16 + l15 + 2 * v + 2;
                xf[pf] = *(const bf16x8*)((const unsigned short*)cur
                           + scol * CELLS + quad * 8);
            }
            #pragma unroll
            for (int of = 0; of < 4; ++of)
                #pragma unroll
                for (int pf = 0; pf < 2; ++pf)
                    acc[of][pf] = __builtin_amdgcn_mfma_f32_16x16x32_bf16(
                        wf[of], xf[pf], acc[of][pf], 0, 0, 0);
        }

        if (u < 6) WRITE(&xs[((u + 1) & 1) * BUFW]);
        __syncthreads();
    }

    unsigned short* Pb = P + (size_t)(kz * 4 + b) * (128 * 4096) + (size_t)h * 64;
    #pragma unroll
    for (int of = 0; of < 4; ++of) {
        const int oc = oc_off + of * 16 + quad * 4;
        #pragma unroll
        for (int pf = 0; pf < 2; ++pf) {
            const int w = px_off + pf * 16 + l15;
            #pragma unroll
            for (int reg = 0; reg < 4; ++reg)
                Pb[(size_t)(oc + reg) * 4096 + w] = f2bf(acc[of][pf][reg]);
        }
    }
}

// ---------------------------------------------------------------------------
// conv2 (1x1, 128->49) + b2 + softmax; reduces KZ bf16 partials + b1.
// grid (64 h, 4 b); block 512. Writes attn fp32 [b][49][h][w].
// ---------------------------------------------------------------------------
__global__ __launch_bounds__(512) void conv2_softmax_kernel(
    const unsigned short* __restrict__ P, const float* __restrict__ w2,
    const float* __restrict__ b2, const float* __restrict__ b1,
    float* __restrict__ attn)
{
    __shared__ float k1s[64 * 140];
    __shared__ float k2s[64 * 56];
    const int h = blockIdx.x, b = blockIdx.y;
    const int t = threadIdx.x;

    for (int f = t; f < OC1 * 64; f += 512) {
        int w = f & 63, oc = f >> 6;
        float s = b1[oc];
        #pragma unroll
        for (int kzi = 0; kzi < KZ; ++kzi) {
            unsigned u = P[(((size_t)(kzi * 4 + b) * 128 + oc) * 64 + h) * 64 + w];
            s += __uint_as_float(u << 16);
        }
        k1s[w * 140 + oc] = s;
    }
    __syncthreads();

    const int w = t & 63, jg = t >> 6;
    float accj[7];
    if (jg < 7) {
        #pragma unroll
        for (int jj = 0; jj < 7; ++jj) accj[jj] = b2[7 * jg + jj];
        const float4* kv = (const float4*)&k1s[w * 140];
        for (int oc4 = 0; oc4 < 32; ++oc4) {
            float4 v = kv[oc4];
            #pragma unroll
            for (int jj = 0; jj < 7; ++jj) {
                const float* wr = w2 + (size_t)(7 * jg + jj) * OC1 + 4 * oc4;
                accj[jj] += v.x * wr[0] + v.y * wr[1] + v.z * wr[2] + v.w * wr[3];
            }
        }
        #pragma unroll
        for (int jj = 0; jj < 7; ++jj) k2s[w * 56 + 7 * jg + jj] = accj[jj];
    } else {
        #pragma unroll
        for (int j = 49; j < 56; ++j) k2s[w * 56 + j] = -1e30f;
    }
    __syncthreads();

    float4 vv[13];
    const float4* k2v = (const float4*)&k2s[w * 56];
    float m = -1e30f;
    #pragma unroll
    for (int i = 0; i < 13; ++i) {
        vv[i] = k2v[i];
        m = fmaxf(m, fmaxf(fmaxf(vv[i].x, vv[i].y), fmaxf(vv[i].z, vv[i].w)));
    }
    float s = 0.f;
    #pragma unroll
    for (int i = 0; i < 13; ++i) {
        s += __expf(vv[i].x - m) + __expf(vv[i].y - m)
           + __expf(vv[i].z - m) + __expf(vv[i].w - m);
    }
    const float inv = 1.f / s;
    if (jg < 7) {
        float* ab = attn + ((size_t)b * NJ * 4096) + (size_t)h * 64 + w;
        #pragma unroll
        for (int jj = 0; jj < 7; ++jj)
            ab[(size_t)(7 * jg + jj) * 4096] = __expf(accj[jj] - m) * inv;
    }
}

// ---------------------------------------------------------------------------
// gather: out[b,c,h,w] = sum_{u,v} attn[b,u*7+v,h,w] * x[b,c,h+2u-6,w+2v-6]
// grid (8 cg, 64 h, 4 b) = 2048 blocks; block 256. Thread = 4 w x 2 ch.
// ---------------------------------------------------------------------------
__global__ __launch_bounds__(256) void gather_kernel(
    const float* __restrict__ x, const float* __restrict__ attn,
    float* __restrict__ out)
{
    __shared__ float as[NJ * 64];
    const int cg = blockIdx.x, h = blockIdx.y, b = blockIdx.z;
    const int t = threadIdx.x;

    const float* ab = attn + ((size_t)(b * NJ) * HW + h) * HW;
    for (int f = t; f < NJ * 64; f += 256)
        as[f] = ab[(f >> 6) * 4096 + (f & 63)];
    __syncthreads();

    const int wp = t & 15, cs = t >> 4;
    const int w0 = wp * 4;
    const int c0 = cg * 32 + cs * 2;
    const float* xb = x + (size_t)(b * CIN + c0) * 4096;

    float ac[2][4];
    #pragma unroll
    for (int c = 0; c < 2; ++c)
        #pragma unroll
        for (int wi = 0; wi < 4; ++wi) ac[c][wi] = 0.f;

    #pragma unroll
    for (int u = 0; u < 7; ++u) {
        const int row = h + 2 * u - 6;
        if ((unsigned)row >= 64u) continue;
        float xr[2][20];
        #pragma unroll
        for (int c = 0; c < 2; ++c) {
            const float4* rp = (const float4*)(xb + (size_t)c * 4096 + row * 64);
            #pragma unroll
            for (int j = 0; j < 5; ++j) {
                const int i4 = wp - 2 + j;
                float4 g = make_float4(0.f, 0.f, 0.f, 0.f);
                if ((unsigned)i4 < 16u) g = rp[i4];
                xr[c][4 * j + 0] = g.x; xr[c][4 * j + 1] = g.y;
                xr[c][4 * j + 2] = g.z; xr[c][4 * j + 3] = g.w;
            }
        }
        #pragma unroll
        for (int v = 0; v < 7; ++v) {
            const float4 a4 = *(const float4*)&as[(u * 7 + v) * 64 + w0];
            const float av[4] = {a4.x, a4.y, a4.z, a4.w};
            #pragma unroll
            for (int wi = 0; wi < 4; ++wi)
                #pragma unroll
                for (int c = 0; c < 2; ++c)
                    ac[c][wi] += av[wi] * xr[c][wi + 2 * v + 2];
        }
    }

    #pragma unroll
    for (int c = 0; c < 2; ++c) {
        float4 st = make_float4(ac[c][0], ac[c][1], ac[c][2], ac[c][3]);
        *(float4*)&out[(size_t)(b * CIN + c0 + c) * 4096 + h * 64 + w0] = st;
    }
}

// ---------------------------------------------------------------------------
// ws: w1t bf16 3,211,264 B | P bf16 [8][4][128][4096] = 33,554,432 B |
//     attn fp32 3,211,264 B  (~40 MB)
// ---------------------------------------------------------------------------
extern "C" void kernel_launch(void* const* d_in, const int* in_sizes, int n_in,
                              void* d_out, int out_size, void* d_ws, size_t ws_size,
                              hipStream_t stream) {
    const float* x  = (const float*)d_in[0];
    const float* w1 = (const float*)d_in[1];
    const float* b1 = (const float*)d_in[2];
    const float* w2 = (const float*)d_in[3];
    const float* b2 = (const float*)d_in[4];
    float* out = (float*)d_out;

    unsigned short* w1t = (unsigned short*)d_ws;
    unsigned short* P   = (unsigned short*)((char*)d_ws + 3211264);
    float* attn         = (float*)((char*)d_ws + 3211264 + 33554432);

    wtrans_kernel<<<256, 256, 0, stream>>>(w1, w1t);
    conv1_mfma_kernel<<<dim3(64, KZ, 4), 256, 0, stream>>>(x, w1t, P);
    conv2_softmax_kernel<<<dim3(HW, 4), 512, 0, stream>>>(P, w2, b2, b1, attn);
    gather_kernel<<<dim3(8, HW, 4), 256, 0, stream>>>(x, attn, out);
}

// Round 10
// 245.460 us; speedup vs baseline: 1.2666x; 1.2666x over previous
//
#include <hip/hip_runtime.h>

#define HW 64
#define CIN 256
#define OC1 128
#define NJ 49
#define KZ 8                 // K-split: each conv1 block does 32 ic x 49 taps
#define CELLW 20             // words per (row,col) cell: 16 ic-words + 4 pad (80B)
#define BUFW (4 * 80 * CELLW)   // 6400 words = 25,600 B per buffer

typedef short bf16x8 __attribute__((ext_vector_type(8)));
typedef float f32x4 __attribute__((ext_vector_type(4)));

__device__ __forceinline__ unsigned f2bf_pack(float a, float b) {
    unsigned ua = __float_as_uint(a);
    ua += 0x7FFF + ((ua >> 16) & 1);
    unsigned ub = __float_as_uint(b);
    ub += 0x7FFF + ((ub >> 16) & 1);
    return (ua >> 16) | (ub & 0xFFFF0000u);
}

__device__ __forceinline__ unsigned short f2bf(float a) {
    unsigned u = __float_as_uint(a);
    u += 0x7FFF + ((u >> 16) & 1);
    return (unsigned short)(u >> 16);
}

// ---------------------------------------------------------------------------
// w1 fp32 [128 oc][256 ic][49 tap] -> w1t bf16 [49][128 oc][256 ic]
// ---------------------------------------------------------------------------
__global__ __launch_bounds__(256) void wtrans_kernel(const float* __restrict__ w1,
                                                     unsigned short* __restrict__ w1t) {
    __shared__ float ws[128 * 49];    // [ic-half 128][tap 49]
    const int oc = blockIdx.x >> 1, ih = blockIdx.x & 1;
    const float4* src = (const float4*)(w1 + ((size_t)oc * 256 + ih * 128) * 49);
    for (int f = threadIdx.x; f < 1568; f += 256)
        *(float4*)&ws[4 * f] = src[f];
    __syncthreads();
    for (int k = threadIdx.x; k < 128 * 49; k += 256) {
        int tap = k / 128, ic = k - tap * 128;   // stride 49 mod 32 = 17: conflict-free
        w1t[((size_t)tap * 128 + oc) * 256 + ih * 128 + ic] = f2bf(ws[ic * 49 + tap]);
    }
}

// ---------------------------------------------------------------------------
// conv1 implicit GEMM, bf16 MFMA 16x16x32, KZ=8, FAT wave tile.
// grid (16 hq, 8 kz, 4 b) = 512 blocks; block 256 = 4 waves.
// Wave: 128 oc x 64 px (one h-row per wave; of=8, pf=4, acc=128 AGPR).
// Rationale (R9 post-mortem): conv1 is operand-feed-bound, bytes/MFMA =
// (M+N)/(M*N); the 128x64 tile gives 384 B/MFMA vs R8's 512, and all 4
// waves load IDENTICAL weight fragments -> L1 serves 3 of 4.
// Staging: ISSUE global loads at u-start into packed regs, taps overlap,
// WRITE to other LDS buffer, 1 barrier per u. wf loads inline per tap.
// P bf16 [kz][b][oc][h][w] partials.
// ---------------------------------------------------------------------------
__global__ __launch_bounds__(256) void conv1_mfma_kernel(
    const float* __restrict__ x, const unsigned short* __restrict__ w1t,
    unsigned short* __restrict__ P)
{
    __shared__ unsigned xs[2 * BUFW];   // 51,200 B

    const int hq = blockIdx.x, kz = blockIdx.y, b = blockIdx.z;
    const int h0 = hq * 4;
    const int t = threadIdx.x;
    const int lane = t & 63, wv = t >> 6;     // wv = h-row within block
    const int l15 = lane & 15, quad = lane >> 4;

    f32x4 acc[8][4];                    // [of][pf] = 128 AGPR
    #pragma unroll
    for (int i = 0; i < 8; ++i)
        #pragma unroll
        for (int j = 0; j < 4; ++j) acc[i][j] = (f32x4){0.f, 0.f, 0.f, 0.f};

    const float* xb = x + ((size_t)b * CIN + kz * 32) * 4096;
    const unsigned short* wbase = w1t + (size_t)l15 * 256 + kz * 32 + quad * 8;

    // staging: 2560 slots (row4 x icq8 x col80) per u; 10 uint2/thread
    uint2 pk[10];

    auto ISSUE = [&](int u) {
        #pragma unroll
        for (int i = 0; i < 10; ++i) {
            int f = t + i * 256;
            int row = f / 640, rem = f - row * 640;
            int icq = rem / 80, col = rem - icq * 80;
            int r = h0 + row + 2 * u - 6;
            int c = col - 8;
            float v0 = 0.f, v1 = 0.f, v2 = 0.f, v3 = 0.f;
            if ((unsigned)r < 64u && (unsigned)c < 64u) {
                const float* p = xb + (size_t)(4 * icq) * 4096 + r * 64 + c;
                v0 = p[0]; v1 = p[4096]; v2 = p[8192]; v3 = p[12288];
            }
            pk[i] = make_uint2(f2bf_pack(v0, v1), f2bf_pack(v2, v3));
        }
    };
    auto WRITE = [&](unsigned* buf) {
        #pragma unroll
        for (int i = 0; i < 10; ++i) {
            int f = t + i * 256;
            int row = f / 640, rem = f - row * 640;
            int icq = rem / 80, col = rem - icq * 80;
            *(uint2*)&buf[(row * 80 + col) * CELLW + 2 * icq] = pk[i];
        }
    };

    ISSUE(0);
    WRITE(&xs[0]);
    __syncthreads();

    for (int u = 0; u < 7; ++u) {
        unsigned* cur = &xs[(u & 1) * BUFW];
        if (u < 6) ISSUE(u + 1);         // loads fly under the tap loop

        #pragma unroll
        for (int v = 0; v < 7; ++v) {
            const unsigned short* wp = wbase + (size_t)(u * 7 + v) * (128 * 256);
            bf16x8 wf[8];
            #pragma unroll
            for (int of = 0; of < 8; ++of)
                wf[of] = *(const bf16x8*)(wp + of * (16 * 256));

            bf16x8 xf[4];
            #pragma unroll
            for (int pf = 0; pf < 4; ++pf) {
                const int scol = pf * 16 + l15 + 2 * v + 2;
                xf[pf] = *(const bf16x8*)((const unsigned short*)cur
                           + ((wv * 80 + scol) * CELLW + quad * 4) * 2);
            }
            #pragma unroll
            for (int of = 0; of < 8; ++of)
                #pragma unroll
                for (int pf = 0; pf < 4; ++pf)
                    acc[of][pf] = __builtin_amdgcn_mfma_f32_16x16x32_bf16(
                        wf[of], xf[pf], acc[of][pf], 0, 0, 0);
        }

        if (u < 6) WRITE(&xs[((u + 1) & 1) * BUFW]);
        __syncthreads();
    }

    unsigned short* Pb = P + (size_t)(kz * 4 + b) * (128 * 4096) + (size_t)(h0 + wv) * 64;
    #pragma unroll
    for (int of = 0; of < 8; ++of) {
        const int oc = of * 16 + quad * 4;
        #pragma unroll
        for (int pf = 0; pf < 4; ++pf) {
            const int w = pf * 16 + l15;
            #pragma unroll
            for (int reg = 0; reg < 4; ++reg)
                Pb[(size_t)(oc + reg) * 4096 + w] = f2bf(acc[of][pf][reg]);
        }
    }
}

// ---------------------------------------------------------------------------
// conv2 (1x1, 128->49) + b2 + softmax; reduces KZ bf16 partials + b1.
// grid (64 h, 4 b); block 512. Writes attn fp32 [b][49][h][w].
// ---------------------------------------------------------------------------
__global__ __launch_bounds__(512) void conv2_softmax_kernel(
    const unsigned short* __restrict__ P, const float* __restrict__ w2,
    const float* __restrict__ b2, const float* __restrict__ b1,
    float* __restrict__ attn)
{
    __shared__ float k1s[64 * 140];
    __shared__ float k2s[64 * 56];
    const int h = blockIdx.x, b = blockIdx.y;
    const int t = threadIdx.x;

    for (int f = t; f < OC1 * 64; f += 512) {
        int w = f & 63, oc = f >> 6;
        float s = b1[oc];
        #pragma unroll
        for (int kzi = 0; kzi < KZ; ++kzi) {
            unsigned u = P[(((size_t)(kzi * 4 + b) * 128 + oc) * 64 + h) * 64 + w];
            s += __uint_as_float(u << 16);
        }
        k1s[w * 140 + oc] = s;
    }
    __syncthreads();

    const int w = t & 63, jg = t >> 6;
    float accj[7];
    if (jg < 7) {
        #pragma unroll
        for (int jj = 0; jj < 7; ++jj) accj[jj] = b2[7 * jg + jj];
        const float4* kv = (const float4*)&k1s[w * 140];
        for (int oc4 = 0; oc4 < 32; ++oc4) {
            float4 v = kv[oc4];
            #pragma unroll
            for (int jj = 0; jj < 7; ++jj) {
                const float* wr = w2 + (size_t)(7 * jg + jj) * OC1 + 4 * oc4;
                accj[jj] += v.x * wr[0] + v.y * wr[1] + v.z * wr[2] + v.w * wr[3];
            }
        }
        #pragma unroll
        for (int jj = 0; jj < 7; ++jj) k2s[w * 56 + 7 * jg + jj] = accj[jj];
    } else {
        #pragma unroll
        for (int j = 49; j < 56; ++j) k2s[w * 56 + j] = -1e30f;
    }
    __syncthreads();

    float4 vv[13];
    const float4* k2v = (const float4*)&k2s[w * 56];
    float m = -1e30f;
    #pragma unroll
    for (int i = 0; i < 13; ++i) {
        vv[i] = k2v[i];
        m = fmaxf(m, fmaxf(fmaxf(vv[i].x, vv[i].y), fmaxf(vv[i].z, vv[i].w)));
    }
    float s = 0.f;
    #pragma unroll
    for (int i = 0; i < 13; ++i) {
        s += __expf(vv[i].x - m) + __expf(vv[i].y - m)
           + __expf(vv[i].z - m) + __expf(vv[i].w - m);
    }
    const float inv = 1.f / s;
    if (jg < 7) {
        float* ab = attn + ((size_t)b * NJ * 4096) + (size_t)h * 64 + w;
        #pragma unroll
        for (int jj = 0; jj < 7; ++jj)
            ab[(size_t)(7 * jg + jj) * 4096] = __expf(accj[jj] - m) * inv;
    }
}

// ---------------------------------------------------------------------------
// gather: out[b,c,h,w] = sum_{u,v} attn[b,u*7+v,h,w] * x[b,c,h+2u-6,w+2v-6]
// grid (8 cg, 64 h, 4 b) = 2048 blocks; block 256. Thread = 4 w x 2 ch.
// ---------------------------------------------------------------------------
__global__ __launch_bounds__(256) void gather_kernel(
    const float* __restrict__ x, const float* __restrict__ attn,
    float* __restrict__ out)
{
    __shared__ float as[NJ * 64];
    const int cg = blockIdx.x, h = blockIdx.y, b = blockIdx.z;
    const int t = threadIdx.x;

    const float* ab = attn + ((size_t)(b * NJ) * HW + h) * HW;
    for (int f = t; f < NJ * 64; f += 256)
        as[f] = ab[(f >> 6) * 4096 + (f & 63)];
    __syncthreads();

    const int wp = t & 15, cs = t >> 4;
    const int w0 = wp * 4;
    const int c0 = cg * 32 + cs * 2;
    const float* xb = x + (size_t)(b * CIN + c0) * 4096;

    float ac[2][4];
    #pragma unroll
    for (int c = 0; c < 2; ++c)
        #pragma unroll
        for (int wi = 0; wi < 4; ++wi) ac[c][wi] = 0.f;

    #pragma unroll
    for (int u = 0; u < 7; ++u) {
        const int row = h + 2 * u - 6;
        if ((unsigned)row >= 64u) continue;
        float xr[2][20];
        #pragma unroll
        for (int c = 0; c < 2; ++c) {
            const float4* rp = (const float4*)(xb + (size_t)c * 4096 + row * 64);
            #pragma unroll
            for (int j = 0; j < 5; ++j) {
                const int i4 = wp - 2 + j;
                float4 g = make_float4(0.f, 0.f, 0.f, 0.f);
                if ((unsigned)i4 < 16u) g = rp[i4];
                xr[c][4 * j + 0] = g.x; xr[c][4 * j + 1] = g.y;
                xr[c][4 * j + 2] = g.z; xr[c][4 * j + 3] = g.w;
            }
        }
        #pragma unroll
        for (int v = 0; v < 7; ++v) {
            const float4 a4 = *(const float4*)&as[(u * 7 + v) * 64 + w0];
            const float av[4] = {a4.x, a4.y, a4.z, a4.w};
            #pragma unroll
            for (int wi = 0; wi < 4; ++wi)
                #pragma unroll
                for (int c = 0; c < 2; ++c)
                    ac[c][wi] += av[wi] * xr[c][wi + 2 * v + 2];
        }
    }

    #pragma unroll
    for (int c = 0; c < 2; ++c) {
        float4 st = make_float4(ac[c][0], ac[c][1], ac[c][2], ac[c][3]);
        *(float4*)&out[(size_t)(b * CIN + c0 + c) * 4096 + h * 64 + w0] = st;
    }
}

// ---------------------------------------------------------------------------
// ws: w1t bf16 3,211,264 B | P bf16 [8][4][128][4096] = 33,554,432 B |
//     attn fp32 3,211,264 B  (~40 MB)
// ---------------------------------------------------------------------------
extern "C" void kernel_launch(void* const* d_in, const int* in_sizes, int n_in,
                              void* d_out, int out_size, void* d_ws, size_t ws_size,
                              hipStream_t stream) {
    const float* x  = (const float*)d_in[0];
    const float* w1 = (const float*)d_in[1];
    const float* b1 = (const float*)d_in[2];
    const float* w2 = (const float*)d_in[3];
    const float* b2 = (const float*)d_in[4];
    float* out = (float*)d_out;

    unsigned short* w1t = (unsigned short*)d_ws;
    unsigned short* P   = (unsigned short*)((char*)d_ws + 3211264);
    float* attn         = (float*)((char*)d_ws + 3211264 + 33554432);

    wtrans_kernel<<<256, 256, 0, stream>>>(w1, w1t);
    conv1_mfma_kernel<<<dim3(16, KZ, 4), 256, 0, stream>>>(x, w1t, P);
    conv2_softmax_kernel<<<dim3(HW, 4), 512, 0, stream>>>(P, w2, b2, b1, attn);
    gather_kernel<<<dim3(8, HW, 4), 256, 0, stream>>>(x, attn, out);
}